// Round 13
// baseline (170.708 us; speedup 1.0000x reference)
//
#include <hip/hip_runtime.h>

// LSTM B=4096, T=512, I=1, H=32 — MFMA, round 13: island-2 (2 batches/wave).
//
// Model (r11/r12 evidence): wall = 512 x single-wave chain; TLP can't shorten
// a wave's own chain (r11 616cy == r12 617cy with different exchanges). r12
// chain = ~320cy in-wave issue + ~300cy latency. This round halves the issue:
//
// 2 batches P,Q per wave at A-rows 0,4 (D: lane(col,0) reg0 = P gates,
// lane(col,1) reg0 = Q gates; 16t+col gate rows). Each lane owns ONE cell:
//   gate redistribution: merged = permlane32_swap(acc_even, acc_odd).x
//     -> lanes g<2: even-tile gate (cell col, batch g);
//        lanes g>=2: odd-tile gate from lane-32 (cell col+16, batch g-2).
//     One VALU op per gate type, no cndmask, all 64 lanes productive.
//   10 trans/lane (was 20), ~24 VALU, 8 MFMA -> issue ~175cy (was ~320).
// h re-pack: cvt f16 + permlane32_swap(h16,h16) (rr.x = cell col of batch g&1,
// rr.y = cell col+16 of batch g&1) + v_perm pack -> same 4x ds_bpermute
// exchange as r12 (bidx formula unchanged; bperm groups 2,3 feed dead A-rows).
// k-perm (cell c <-> k=2*(c&15)+(c>>4)) and folded gate scales unchanged.

typedef float f32x4 __attribute__((ext_vector_type(4)));
typedef _Float16 f16x8 __attribute__((ext_vector_type(8)));
typedef unsigned int v2u __attribute__((ext_vector_type(2)));

#define L2E 1.44269504088896340736f
#define MFMA16(a, b, c) __builtin_amdgcn_mfma_f32_16x16x32_f16((a), (b), (c), 0, 0, 0)

union H2U { _Float16 h; unsigned short u; };
union FRAG { int i[4]; f16x8 h; };
union F2U { float f; unsigned u; };

__device__ __forceinline__ float sig_pre(float t) {   // t = -L2E*g
    return __builtin_amdgcn_rcpf(1.0f + __builtin_amdgcn_exp2f(t));
}
__device__ __forceinline__ float tanh_pre(float t) {  // t = -2*L2E*g
    return fmaf(__builtin_amdgcn_rcpf(1.0f + __builtin_amdgcn_exp2f(t)), 2.0f, -1.0f);
}

// permlane32_swap(d,s).x = {d[0:31], s[0:31]}: lanes<32 keep d, lanes>=32 get
// s from (lane-32).  (builtin verified r5/r12-era; NOT inline asm)
__device__ __forceinline__ float merge_gates(float even, float odd) {
    F2U a, b; a.f = even; b.f = odd;
    v2u r = __builtin_amdgcn_permlane32_swap(a.u, b.u, false, false);
    F2U o; o.u = r.x;
    return o.f;
}

__global__ __launch_bounds__(256) void lstm_mfma_kernel(
    const float* __restrict__ x,      // [B, 512]
    const float* __restrict__ W_ih,   // [128]
    const float* __restrict__ W_hh,   // [128, 32]
    const float* __restrict__ b_ih,   // [128]
    const float* __restrict__ b_hh,   // [128]
    const float* __restrict__ W_lin,  // [32]
    const float* __restrict__ b_lin,  // [1]
    float* __restrict__ out,          // [B]
    int B)
{
    const int tid  = (int)threadIdx.x;
    const int wv   = tid >> 6;            // wave in block (4 waves, 2 batches each)
    const int lane = tid & 63;
    const int col  = lane & 15;           // tile col = A-row candidate
    const int g    = lane >> 4;           // k-group; g&1 = this lane's batch slot

    // bpermute byte-indices (identical to r12): word j <- lane 16*(col>>2)+4g+j
    int bidx[4];
#pragma unroll
    for (int j = 0; j < 4; ++j) bidx[j] = (16 * (col >> 2) + 4 * g + j) << 2;

    // B-fragments for all 8 tiles, fp16, scales folded (identical to r12).
    f16x8 bf[8];
    f32x4 biasC[8];
#pragma unroll
    for (int t = 0; t < 8; ++t) {
        const int gr = t * 16 + col;
        const float sc = (t == 4 || t == 5) ? (-2.0f * L2E) : (-L2E);
        const float* wr = &W_hh[gr * 32];
        f16x8 bb;
#pragma unroll
        for (int j = 0; j < 4; ++j) {
            bb[2 * j + 0] = (_Float16)(wr[4 * g + j] * sc);
            bb[2 * j + 1] = (_Float16)(wr[16 + 4 * g + j] * sc);
        }
        bf[t] = bb;
        const float bbias = (b_ih[gr] + b_hh[gr]) * sc;
        biasC[t] = f32x4{bbias, 0.0f, 0.0f, 0.0f};     // bias only in reg0
    }

    // per-lane cell constants: this lane updates cell col+16*(g>>1) of batch g&1
    const int cell = col + 16 * (g >> 1);
    const float wI = W_ih[cell]      * (-L2E);
    const float wF = W_ih[32 + cell] * (-L2E);
    const float wG = W_ih[64 + cell] * (-2.0f * L2E);
    const float wO = W_ih[96 + cell] * (-L2E);
    const bool useQ = (g & 1) != 0;

    const int bP  = blockIdx.x * 8 + wv * 2;
    const int bQ  = bP + 1;
    const int bPc = bP < B ? bP : (B - 1);
    const int bQc = bQ < B ? bQ : (B - 1);
    const float* xbP = x + (size_t)bPc * 512;
    const float* xbQ = x + (size_t)bQc * 512;

    float4 xAP = *reinterpret_cast<const float4*>(xbP);
    float4 xBP = *reinterpret_cast<const float4*>(xbP + 4);
    float4 xAQ = *reinterpret_cast<const float4*>(xbQ);
    float4 xBQ = *reinterpret_cast<const float4*>(xbQ + 4);

    float cc = 0.0f, hh = 0.0f;
    unsigned hu = 0u;                     // packed fp16 pair (h(0)=0)

    for (int tc = 0; tc < 64; ++tc) {
        const int nbase = ((tc + 1) & 63) * 8;
        const float4 nAP = *reinterpret_cast<const float4*>(xbP + nbase);
        const float4 nBP = *reinterpret_cast<const float4*>(xbP + nbase + 4);
        const float4 nAQ = *reinterpret_cast<const float4*>(xbQ + nbase);
        const float4 nBQ = *reinterpret_cast<const float4*>(xbQ + nbase + 4);
        const float xtsP[8] = {xAP.x, xAP.y, xAP.z, xAP.w, xBP.x, xBP.y, xBP.z, xBP.w};
        const float xtsQ[8] = {xAQ.x, xAQ.y, xAQ.z, xAQ.w, xBQ.x, xBQ.y, xBQ.z, xBQ.w};

#pragma unroll
        for (int s = 0; s < 8; ++s) {
            // exchange: 4x bpermute of the packed h pairs -> A-fragment
            FRAG fr;
#pragma unroll
            for (int j = 0; j < 4; ++j)
                fr.i[j] = __builtin_amdgcn_ds_bpermute(bidx[j], (int)hu);

            // 8 independent MFMAs; reg0 rows 0/4 = batches P/Q
            f32x4 acc[8];
#pragma unroll
            for (int t = 0; t < 8; ++t) acc[t] = MFMA16(fr.h, bf[t], biasC[t]);

            // one permlane32_swap per gate type -> every lane holds ITS gate
            float gi = merge_gates(acc[0][0], acc[1][0]);
            float gf = merge_gates(acc[2][0], acc[3][0]);
            float gG = merge_gates(acc[4][0], acc[5][0]);
            float go = merge_gates(acc[6][0], acc[7][0]);

            const float xt = useQ ? xtsQ[s] : xtsP[s];
            gi = fmaf(xt, wI, gi);
            gf = fmaf(xt, wF, gf);
            gG = fmaf(xt, wG, gG);
            go = fmaf(xt, wO, go);

            const float i_ = sig_pre(gi);
            const float f_ = sig_pre(gf);
            const float G_ = tanh_pre(gG);
            const float o_ = sig_pre(go);

            cc = fmaf(f_, cc, i_ * G_);
            hh = o_ * tanh_pre(cc * (-2.0f * L2E));

            // pack next A-pair: rr.x = cell col (batch g&1), rr.y = cell col+16
            H2U hc; hc.h = (_Float16)hh;
            v2u rr = __builtin_amdgcn_permlane32_swap((unsigned)hc.u, (unsigned)hc.u,
                                                      false, false);
            hu = __builtin_amdgcn_perm(rr.y, rr.x, 0x05040100u);
        }
        xAP = nAP; xBP = nBP; xAQ = nAQ; xBQ = nBQ;
    }

    // out[b] = sum_cells h*W_lin + b_lin: xor-reduce 16-group, then g <-> g+2
    float part = hh * W_lin[cell];
    part += __shfl_xor(part, 1, 64);
    part += __shfl_xor(part, 2, 64);
    part += __shfl_xor(part, 4, 64);
    part += __shfl_xor(part, 8, 64);
    part += __shfl_xor(part, 32, 64);     // combine cells 0-15 with 16-31
    if (col == 0 && g == 0 && bP < B) out[bP] = part + b_lin[0];
    if (col == 0 && g == 1 && bQ < B) out[bQ] = part + b_lin[0];
}

extern "C" void kernel_launch(void* const* d_in, const int* in_sizes, int n_in,
                              void* d_out, int out_size, void* d_ws, size_t ws_size,
                              hipStream_t stream) {
    const float* x     = (const float*)d_in[0];
    const float* W_ih  = (const float*)d_in[1];
    const float* W_hh  = (const float*)d_in[2];
    const float* b_ih  = (const float*)d_in[3];
    const float* b_hh  = (const float*)d_in[4];
    const float* W_lin = (const float*)d_in[5];
    const float* b_lin = (const float*)d_in[6];
    float* out = (float*)d_out;

    const int B = in_sizes[0] / 512;          // x is [B, 512, 1]
    const int blocks = (B + 7) / 8;           // 8 batches per 256-thread block

    lstm_mfma_kernel<<<blocks, 256, 0, stream>>>(x, W_ih, W_hh, b_ih, b_hh,
                                                 W_lin, b_lin, out, B);
}

// Round 14
// 120.362 us; speedup vs baseline: 1.4183x; 1.4183x over previous
//
#include <hip/hip_runtime.h>

// LSTM B=4096, T=512, I=1, H=32 — MFMA, round 14: r11 base minus lo-residual.
//
// r13 post-mortem: island-2 added 7+ cross-lane VALU ops (permlane hazard
// waits) to the chain -> C 616->800cy. Reverted to r11 (131us, C=616).
//
// r11/r12 equality (616 vs 617cy with totally different exchanges) shows the
// chain floor: exchange ~180 + MFMA ~80 + 2 serial trans chains ~140 + issue.
// This round: pure chain deletions on r11 —
//  1. h carried as fp16 RNE ONLY (no lo residual): r12/r13 proved absmax
//     stays 9.8e-4. Deletes per step: lo split/cvt/pack, one ds_write_b16,
//     and the acc[0]+acc[1] combine (4 adds on the MFMA->gate path).
//     Lo rows zeroed once; D-rows r%4==1 are dead.
//
// Structure (verified r9/r11): block = 128 threads = 2 waves, 4 batches.
// Wave w owns cells col+16w (1 cell/lane) via gate tiles {w,w+2,w+4,w+6}.
// A-rows: 4b = batch b h (fp16), others zero/alias (dead D-rows). k-perm:
// cell c <-> k = 2*(c&15)+(c>>4). Gate scales folded into W_ih/W_hh/bias.
// Double-buffered LDS, one __syncthreads per step.

typedef float f32x4 __attribute__((ext_vector_type(4)));
typedef _Float16 f16x8 __attribute__((ext_vector_type(8)));

#define L2E 1.44269504088896340736f
#define MFMA16(a, b, c) __builtin_amdgcn_mfma_f32_16x16x32_f16((a), (b), (c), 0, 0, 0)

union H2U { _Float16 h; unsigned short u; };

__device__ __forceinline__ float sig_pre(float t) {   // t = -L2E*g
    return __builtin_amdgcn_rcpf(1.0f + __builtin_amdgcn_exp2f(t));
}
__device__ __forceinline__ float tanh_pre(float t) {  // t = -2*L2E*g
    return fmaf(__builtin_amdgcn_rcpf(1.0f + __builtin_amdgcn_exp2f(t)), 2.0f, -1.0f);
}

#define RSTR 40   // u16 row stride: 80B rows, 16B-aligned, banks spread

__global__ __launch_bounds__(128, 2) void lstm_mfma_kernel(
    const float* __restrict__ x,      // [B, 512]
    const float* __restrict__ W_ih,   // [128]
    const float* __restrict__ W_hh,   // [128, 32]
    const float* __restrict__ b_ih,   // [128]
    const float* __restrict__ b_hh,   // [128]
    const float* __restrict__ W_lin,  // [32]
    const float* __restrict__ b_lin,  // [1]
    float* __restrict__ out,          // [B]
    int B)
{
    __shared__ unsigned short Hb[2][8][RSTR];   // [buf][2*batch + hi/lo][RSTR]
    __shared__ float plds[4][2];

    const int tid  = (int)threadIdx.x;
    const int w    = tid >> 6;            // wave 0/1 -> cells col / col+16
    const int lane = tid & 63;
    const int col  = lane & 15;           // tile col = A-row index
    const int g    = lane >> 4;           // batch slot & k-group

    // zero both buffers (h(0)=0; lo rows stay zero FOREVER — never rewritten)
    for (int i = tid; i < 2 * 8 * RSTR; i += 128)
        ((unsigned short*)Hb)[i] = 0;

    // A-row content: col%4==0 -> h(batch col/4); ==1 -> zero row; ==2/3 -> alias 0/1
    const int m4   = col & 3;
    const int rrow = (m4 == 0) ? 2 * (col >> 2)
                   : (m4 == 1) ? 2 * (col >> 2) + 1
                   : (m4 - 2);
    const unsigned short* Ard0 = &Hb[0][rrow][8 * g];   // 16B-aligned
    const unsigned short* Ard1 = &Hb[1][rrow][8 * g];

    // h publish: this lane's cell -> u16 at k = 2*col + w, row (g, hi)
    unsigned short* Whi0 = &Hb[0][2 * g][2 * col + w];
    unsigned short* Whi1 = &Hb[1][2 * g][2 * col + w];

    // B-fragments for this wave's 4 tiles (t = w+2j; j = i,f,G,o): fp16,
    // scales folded. u16 pair jj = (cell g*4+jj, cell g*4+jj+16)  [k-perm]
    f16x8 bf[4];
    float wihs[4];
    f32x4 biasC[4];
#pragma unroll
    for (int j = 0; j < 4; ++j) {
        const int t  = w + 2 * j;
        const int gr = t * 16 + col;
        const float sc = (j == 2) ? (-2.0f * L2E) : (-L2E);
        const float* wr = &W_hh[gr * 32];
        float4 wA = *reinterpret_cast<const float4*>(&wr[g * 4]);       // cells g4+0..3
        float4 wB = *reinterpret_cast<const float4*>(&wr[g * 4 + 16]);  // cells g4+16..19
        f16x8 bb;
        bb[0] = (_Float16)(wA.x * sc); bb[1] = (_Float16)(wB.x * sc);
        bb[2] = (_Float16)(wA.y * sc); bb[3] = (_Float16)(wB.y * sc);
        bb[4] = (_Float16)(wA.z * sc); bb[5] = (_Float16)(wB.z * sc);
        bb[6] = (_Float16)(wA.w * sc); bb[7] = (_Float16)(wB.w * sc);
        bf[j] = bb;
        wihs[j] = W_ih[gr] * sc;
        const float bbias = (b_ih[gr] + b_hh[gr]) * sc;
        biasC[j] = f32x4{bbias, 0.0f, 0.0f, 0.0f};     // bias only in reg0
    }

    const int b_glob = blockIdx.x * 4 + g;
    const int bc     = b_glob < B ? b_glob : (B - 1);
    const float* xb  = x + (size_t)bc * 512;

    float4 xA = *reinterpret_cast<const float4*>(xb);
    float4 xB = *reinterpret_cast<const float4*>(xb + 4);

    float cc = 0.0f, hh = 0.0f;
    __syncthreads();                                    // zero-init visible

    for (int tc = 0; tc < 64; ++tc) {
        const int nbase = ((tc + 1) & 63) * 8;
        const float4 nA = *reinterpret_cast<const float4*>(xb + nbase);
        const float4 nB = *reinterpret_cast<const float4*>(xb + nbase + 4);
        const float xts[8] = {xA.x, xA.y, xA.z, xA.w, xB.x, xB.y, xB.z, xB.w};

#pragma unroll
        for (int s = 0; s < 8; ++s) {
            const float xt = xts[s];

            // even global step reads buf0 (h starts in buf0), writes buf1
            const f16x8 af = *reinterpret_cast<const f16x8*>((s & 1) ? Ard1 : Ard0);

            // single pass: 4 independent MFMAs; reg0 = h*W (+bias); reg1 dead
            f32x4 acc[4];
#pragma unroll
            for (int j = 0; j < 4; ++j) acc[j] = MFMA16(af, bf[j], biasC[j]);

            float gt[4];
#pragma unroll
            for (int j = 0; j < 4; ++j)
                gt[j] = fmaf(xt, wihs[j], acc[j][0]);

            const float i_ = sig_pre(gt[0]);
            const float f_ = sig_pre(gt[1]);
            const float G_ = tanh_pre(gt[2]);
            const float o_ = sig_pre(gt[3]);

            cc = fmaf(f_, cc, i_ * G_);
            hh = o_ * tanh_pre(cc * (-2.0f * L2E));

            // publish h as fp16 (RNE) to the OTHER buffer — single b16 store
            H2U hc; hc.h = (_Float16)hh;
            *((s & 1) ? Whi0 : Whi1) = hc.u;
            __syncthreads();
        }
        xA = nA; xB = nB;
    }

    // out[b] = sum_cells h*W_lin + b_lin: 16-lane reduce, then cross-wave via LDS
    float part = hh * W_lin[col + 16 * w];
#pragma unroll
    for (int off = 8; off; off >>= 1) part += __shfl_xor(part, off, 64);
    if (col == 0) plds[g][w] = part;
    __syncthreads();
    if (w == 0 && col == 0 && b_glob < B)
        out[b_glob] = plds[g][0] + plds[g][1] + b_lin[0];
}

extern "C" void kernel_launch(void* const* d_in, const int* in_sizes, int n_in,
                              void* d_out, int out_size, void* d_ws, size_t ws_size,
                              hipStream_t stream) {
    const float* x     = (const float*)d_in[0];
    const float* W_ih  = (const float*)d_in[1];
    const float* W_hh  = (const float*)d_in[2];
    const float* b_ih  = (const float*)d_in[3];
    const float* b_hh  = (const float*)d_in[4];
    const float* W_lin = (const float*)d_in[5];
    const float* b_lin = (const float*)d_in[6];
    float* out = (float*)d_out;

    const int B = in_sizes[0] / 512;          // x is [B, 512, 1]
    const int blocks = (B + 3) / 4;           // 4 batches per 128-thread block

    lstm_mfma_kernel<<<blocks, 128, 0, stream>>>(x, W_ih, W_hh, b_ih, b_hh,
                                                 W_lin, b_lin, out, B);
}